// Round 1
// baseline (1506.160 us; speedup 1.0000x reference)
//
#include <hip/hip_runtime.h>
#include <math.h>

#define NSTEPS 500
#define BATCH  1024
#define DX     32
#define DW     32
#define HDIM   128
#define BETA   0.5f
#define EPSG   1e-4f
#define RPB    2      // rows (batch elements) per block

__device__ __forceinline__ float tanh_fast(float x) {
    // tanh(x) = (e^{2x}-1)/(e^{2x}+1); clamp so e^{2x} cannot overflow.
    float xc = fminf(fmaxf(x, -15.f), 15.f);
    float e  = __expf(2.f * xc);
    return (e - 1.f) / (e + 1.f);
}

__global__ __launch_bounds__(256, 2)
void sde_kernel(const float* __restrict__ x0, const float* __restrict__ ts,
                const float* __restrict__ dWs,
                const float* __restrict__ W1, const float* __restrict__ b1,
                const float* __restrict__ W2, const float* __restrict__ b2,
                const float* __restrict__ W3, const float* __restrict__ b3,
                const float* __restrict__ G,  const float* __restrict__ mu,
                const float* __restrict__ vt, float* __restrict__ out)
{
    __shared__ __align__(16) float sx  [RPB][DX];
    __shared__ __align__(16) float sh1 [RPB][HDIM];
    __shared__ __align__(16) float sh2 [RPB][HDIM];
    __shared__ __align__(16) float spart[2][RPB][HDIM];
    __shared__ __align__(16) float spart3[8][RPB][DX];
    __shared__ __align__(16) float sprra[RPB][2][DX];
    __shared__ __align__(16) float sr  [RPB][DX];
    __shared__ __align__(16) float sra [RPB][DX];
    __shared__ __align__(16) float sv  [RPB][DX];
    __shared__ __align__(16) float su  [RPB][DX];
    __shared__ __align__(16) float sdWu[RPB][DX];
    __shared__ __align__(16) float sGt [DX][DX];   // sGt[k][d] = G[d][k]
    __shared__ __align__(16) float sa  [DX][DX];   // a = G G^T (symmetric), index [k][d]
    __shared__ __align__(16) float smu [DX];
    __shared__ __align__(16) float svt [DX];

    const int tid = threadIdx.x;
    const int r0  = blockIdx.x * RPB;

    // ---- per-thread weight ownership (registers) ----
    const int j  = tid & 127;   // H column (layers 1,2)
    const int kp = tid >> 7;    // K-half (layers 1,2): 0/1
    const int d3 = tid & 31;    // output dim (layer 3)
    const int kq = tid >> 5;    // K-eighth (layer 3): 0..7

    float w1r[17];
    if (kp == 0) {
        #pragma unroll
        for (int k = 0; k < 17; ++k) w1r[k] = W1[k * HDIM + j];          // rows 0..16 of [t,x]
    } else {
        #pragma unroll
        for (int k = 0; k < 16; ++k) w1r[k] = W1[(17 + k) * HDIM + j];   // rows 17..32
        w1r[16] = 0.f;
    }
    float w2r[64];
    #pragma unroll
    for (int k = 0; k < 64; ++k) w2r[k] = W2[(kp * 64 + k) * HDIM + j];
    float w3r[16];
    #pragma unroll
    for (int k = 0; k < 16; ++k) w3r[k] = W3[(kq * 16 + k) * DW + d3];
    const float b1r = b1[j];
    const float b2r = b2[j];
    const float b3r = b3[d3];

    // ---- shared init ----
    if (tid < RPB * DX) {
        int row = tid >> 5, d = tid & 31;
        sx[row][d] = x0[(r0 + row) * DX + d];
    }
    for (int idx = tid; idx < DX * DX; idx += 256) {
        int i = idx >> 5, k = idx & 31;
        sGt[k][i] = G[i * DW + k];     // transpose into LDS
    }
    if (tid < DX) { smu[tid] = mu[tid]; svt[tid] = vt[tid]; }
    __syncthreads();
    for (int idx = tid; idx < DX * DX; idx += 256) {
        int i = idx >> 5, jj = idx & 31;
        float acc = 0.f;
        #pragma unroll
        for (int k = 0; k < DW; ++k) acc += sGt[k][i] * sGt[k][jj];
        sa[i][jj] = acc;               // a[i][jj] = sum_k G[i][k] G[jj][k]
    }
    __syncthreads();

    const float T = ts[NSTEPS];
    float tcur = ts[0];
    float llr = 0.f;

    float* xs_out = out;
    float* vs_out = out + (size_t)NSTEPS * BATCH * DX;
    float* ll_out = out + (size_t)2 * NSTEPS * BATCH * DX;

    for (int s = 0; s < NSTEPS; ++s) {
        const float tn     = ts[s + 1];
        const float dt     = tn - tcur;
        const float sqdt   = sqrtf(dt);
        const float invrem = 1.0f / (T - tcur + EPSG);

        // ---- stage 0: r and scaled dW (no barrier needed before phase A) ----
        if (tid < 64) {
            int row = tid >> 5, d = tid & 31;
            sr[row][d] = (svt[d] - sx[row][d]) * invrem;
        } else if (tid < 128) {
            int row = (tid - 64) >> 5, d = tid & 31;
            sdWu[row][d] = dWs[(size_t)s * (BATCH * DX) + (size_t)(r0 + row) * DX + d] * sqdt;
        }

        // ---- phase A: layer-1 partials (inp = [t, x]) ----
        {
            float a0, a1;
            if (kp == 0) {
                a0 = tcur * w1r[0];
                a1 = tcur * w1r[0];
                #pragma unroll
                for (int k = 0; k < 16; ++k) {
                    a0 += sx[0][k] * w1r[k + 1];
                    a1 += sx[1][k] * w1r[k + 1];
                }
            } else {
                a0 = 0.f; a1 = 0.f;
                #pragma unroll
                for (int k = 0; k < 16; ++k) {
                    a0 += sx[0][16 + k] * w1r[k];
                    a1 += sx[1][16 + k] * w1r[k];
                }
            }
            spart[kp][0][j] = a0;
            spart[kp][1][j] = a1;
        }
        __syncthreads();
        {
            int row = tid >> 7, jj = tid & 127;
            sh1[row][jj] = tanh_fast(spart[0][row][jj] + spart[1][row][jj] + b1r);
        }
        __syncthreads();

        // ---- phase B: layer-2 partials (weights in registers, h1 broadcast b128) ----
        {
            const float* h0p = &sh1[0][kp * 64];
            const float* h1p = &sh1[1][kp * 64];
            float a0 = 0.f, a1 = 0.f;
            #pragma unroll
            for (int k = 0; k < 64; k += 4) {
                float4 ha = *(const float4*)(h0p + k);
                float4 hb = *(const float4*)(h1p + k);
                a0 += ha.x * w2r[k] + ha.y * w2r[k + 1] + ha.z * w2r[k + 2] + ha.w * w2r[k + 3];
                a1 += hb.x * w2r[k] + hb.y * w2r[k + 1] + hb.z * w2r[k + 2] + hb.w * w2r[k + 3];
            }
            spart[kp][0][j] = a0;
            spart[kp][1][j] = a1;
        }
        __syncthreads();
        {
            int row = tid >> 7, jj = tid & 127;
            sh2[row][jj] = tanh_fast(spart[0][row][jj] + spart[1][row][jj] + b2r);
        }
        __syncthreads();

        // ---- phase C: layer-3 partials (all threads) + r@a partials (half) ----
        {
            const float* h0p = &sh2[0][kq * 16];
            const float* h1p = &sh2[1][kq * 16];
            float c0 = 0.f, c1 = 0.f;
            #pragma unroll
            for (int k = 0; k < 16; k += 4) {
                float4 ha = *(const float4*)(h0p + k);
                float4 hb = *(const float4*)(h1p + k);
                c0 += ha.x * w3r[k] + ha.y * w3r[k + 1] + ha.z * w3r[k + 2] + ha.w * w3r[k + 3];
                c1 += hb.x * w3r[k] + hb.y * w3r[k + 1] + hb.z * w3r[k + 2] + hb.w * w3r[k + 3];
            }
            spart3[kq][0][d3] = c0;
            spart3[kq][1][d3] = c1;
        }
        if (tid < 128) {
            int d = tid & 31, kr = (tid >> 5) & 1, row = tid >> 6;
            const float* rp = &sr[row][kr * 16];
            float acc = 0.f;
            #pragma unroll
            for (int k = 0; k < 16; k += 4) {
                float4 r4 = *(const float4*)(rp + k);
                int kb = kr * 16 + k;
                acc += r4.x * sa[kb][d] + r4.y * sa[kb + 1][d]
                     + r4.z * sa[kb + 2][d] + r4.w * sa[kb + 3][d];
            }
            sprra[row][kr][d] = acc;
        }
        __syncthreads();

        // ---- phase C combine: v, ra, u, Gval reduction ----
        if (tid < 64) {
            int row = tid >> 5, d = tid & 31;
            float v = b3r;
            #pragma unroll
            for (int q = 0; q < 8; ++q) v += spart3[q][row][d];
            float ra = sprra[row][0][d] + sprra[row][1][d];
            float xv = sx[row][d];
            float rv = sr[row][d];
            float fb = BETA * (smu[d] - xv);
            sv[row][d]  = v;
            sra[row][d] = ra;
            su[row][d]  = v * dt + sdWu[row][d];   // u = v*dt + dW*sqrt(dt)
            float term = fb * rv - 0.5f * rv * ra;
            term += __shfl_down(term, 16);
            term += __shfl_down(term, 8);
            term += __shfl_down(term, 4);
            term += __shfl_down(term, 2);
            term += __shfl_down(term, 1);
            if (d == 0) llr += term * dt;           // valid at lanes 0 (row0) and 32 (row1)
        }
        __syncthreads();

        // ---- phase D: x update + outputs ----
        if (tid < 64) {
            int row = tid >> 5, d = tid & 31;
            float acc = 0.f;
            #pragma unroll
            for (int k = 0; k < 32; k += 4) {
                float4 u4 = *(const float4*)&su[row][k];
                acc += u4.x * sGt[k][d] + u4.y * sGt[k + 1][d]
                     + u4.z * sGt[k + 2][d] + u4.w * sGt[k + 3][d];
            }
            float xv = sx[row][d];
            float fb = BETA * (smu[d] - xv);
            float xn = xv + (fb + sra[row][d]) * dt + acc;
            sx[row][d] = xn;
            size_t off = (size_t)s * (BATCH * DX) + (size_t)(r0 + row) * DX + d;
            xs_out[off] = xn;
            vs_out[off] = sv[row][d];
        }
        tcur += dt;
        __syncthreads();
    }

    if (tid == 0)  ll_out[r0]     = llr;
    if (tid == 32) ll_out[r0 + 1] = llr;
}

extern "C" void kernel_launch(void* const* d_in, const int* in_sizes, int n_in,
                              void* d_out, int out_size, void* d_ws, size_t ws_size,
                              hipStream_t stream) {
    const float* x0 = (const float*)d_in[0];
    const float* ts = (const float*)d_in[1];
    const float* dWs = (const float*)d_in[2];
    const float* W1 = (const float*)d_in[3];
    const float* b1 = (const float*)d_in[4];
    const float* W2 = (const float*)d_in[5];
    const float* b2 = (const float*)d_in[6];
    const float* W3 = (const float*)d_in[7];
    const float* b3 = (const float*)d_in[8];
    const float* G  = (const float*)d_in[9];
    const float* mu = (const float*)d_in[10];
    const float* vt = (const float*)d_in[11];
    hipLaunchKernelGGL(sde_kernel, dim3(BATCH / RPB), dim3(256), 0, stream,
                       x0, ts, dWs, W1, b1, W2, b2, W3, b3, G, mu, vt, (float*)d_out);
}